// Round 1
// baseline (867.839 us; speedup 1.0000x reference)
//
#include <hip/hip_runtime.h>

// GCN 2-layer forward. N=100000 nodes, E=1600000 edges, 128->64->64.
// Pipeline: deg(dst)+1 -> dinv=rsqrt -> h1=x@W1 -> scatter(h1*norm) ->
//           epi1(+h1*dinv^2+b1, relu) -> h2=out1@W2 -> scatter -> epi2(+b2).

__global__ __launch_bounds__(256) void deg_kernel(const int* __restrict__ dst,
                                                  int* __restrict__ deg, int nE) {
  int e = blockIdx.x * 256 + threadIdx.x;
  if (e < nE) atomicAdd(&deg[dst[e]], 1);
}

__global__ __launch_bounds__(256) void dinv_kernel(const int* __restrict__ deg,
                                                   float* __restrict__ dinv, int n) {
  int i = blockIdx.x * 256 + threadIdx.x;
  if (i < n) dinv[i] = rsqrtf((float)deg[i] + 1.0f);
}

// H[N,64] = X[N,K] @ W[K,64].  Per lane: 4 rows x 4 channels register tile.
// W staged in LDS as float4 (K*16 float4 = 32KB for K=128).
template <int K>
__global__ __launch_bounds__(256) void gemm64(const float* __restrict__ X,
                                              const float* __restrict__ W,
                                              float* __restrict__ H, int N) {
  __shared__ float4 sW[K * 16];
  for (int i = threadIdx.x; i < K * 16; i += 256)
    sW[i] = reinterpret_cast<const float4*>(W)[i];
  __syncthreads();
  const int wave = threadIdx.x >> 6, lane = threadIdx.x & 63;
  const int rg = lane >> 4;        // row group 0..3
  const int cl = lane & 15;        // channel group: channels cl*4..cl*4+3
  const int row0 = blockIdx.x * 64 + wave * 16 + rg * 4;
  if (row0 >= N) return;
  const float4* Xv = reinterpret_cast<const float4*>(X);
  const float4* xp[4];
#pragma unroll
  for (int r = 0; r < 4; ++r) {
    int row = min(row0 + r, N - 1);  // clamp loads; stores guarded below
    xp[r] = Xv + (size_t)row * (K / 4);
  }
  float acc[4][4] = {};
#pragma unroll 4
  for (int k4 = 0; k4 < K / 4; ++k4) {
    float4 xv[4];
#pragma unroll
    for (int r = 0; r < 4; ++r) xv[r] = xp[r][k4];
#pragma unroll
    for (int j = 0; j < 4; ++j) {
      float4 w = sW[(k4 * 4 + j) * 16 + cl];
#pragma unroll
      for (int r = 0; r < 4; ++r) {
        float xs = (&xv[r].x)[j];
        acc[r][0] += xs * w.x;
        acc[r][1] += xs * w.y;
        acc[r][2] += xs * w.z;
        acc[r][3] += xs * w.w;
      }
    }
  }
#pragma unroll
  for (int r = 0; r < 4; ++r) {
    int row = row0 + r;
    if (row < N)
      reinterpret_cast<float4*>(H)[(size_t)row * 16 + cl] =
          make_float4(acc[r][0], acc[r][1], acc[r][2], acc[r][3]);
  }
}

// One wave per edge (64 lanes = 64 channels): agg[dst] += h[src] * dinv[s]*dinv[d]
__global__ __launch_bounds__(256) void scatter_kernel(
    const float* __restrict__ h, const int* __restrict__ src,
    const int* __restrict__ dst, const float* __restrict__ dinv,
    float* __restrict__ agg, int nE) {
  int idx = blockIdx.x * 256 + threadIdx.x;
  int e = idx >> 6;
  if (e >= nE) return;
  int c = idx & 63;
  int s = src[e], d = dst[e];
  float nrm = dinv[s] * dinv[d];
  atomicAdd(agg + (((size_t)d) << 6) + c, h[(((size_t)s) << 6) + c] * nrm);
}

// agg[i,c] = (relu?)(agg[i,c] + h[i,c]*dinv[i]^2 + b[c])
template <bool RELU>
__global__ __launch_bounds__(256) void epi_kernel(float* __restrict__ agg,
                                                  const float* __restrict__ h,
                                                  const float* __restrict__ dinv,
                                                  const float* __restrict__ b,
                                                  int n64) {
  int idx = blockIdx.x * 256 + threadIdx.x;
  if (idx >= n64) return;
  int i = idx >> 6, c = idx & 63;
  float di = dinv[i];
  float v = agg[idx] + h[idx] * di * di + b[c];
  agg[idx] = RELU ? fmaxf(v, 0.f) : v;
}

extern "C" void kernel_launch(void* const* d_in, const int* in_sizes, int n_in,
                              void* d_out, int out_size, void* d_ws, size_t ws_size,
                              hipStream_t stream) {
  const float* x  = (const float*)d_in[0];
  const int*   ei = (const int*)d_in[1];   // (2, E) int32 per harness convention
  const float* W1 = (const float*)d_in[2];
  const float* b1 = (const float*)d_in[3];
  const float* W2 = (const float*)d_in[4];
  const float* b2 = (const float*)d_in[5];
  const int N = in_sizes[0] / 128;
  const int E = in_sizes[1] / 2;
  const int* src = ei;
  const int* dst = ei + E;

  char* ws = (char*)d_ws;
  int*   deg  = (int*)ws;                       // N ints        @ 0
  float* dinv = (float*)(ws + (1 << 19));       // N floats      @ 512KB
  float* bufA = (float*)(ws + (1 << 20));       // N*64 floats   @ 1MB
  size_t fsz = (size_t)N * 64 * sizeof(float);  // 25,600,000 B (1024-aligned)
  float* bufB = (float*)(ws + (1 << 20) + fsz); // N*64 floats
  float* out = (float*)d_out;

  const int n64 = N * 64;

  // degree + dinv (shared across both layers)
  hipMemsetAsync(deg, 0, N * sizeof(int), stream);
  deg_kernel<<<(E + 255) / 256, 256, 0, stream>>>(dst, deg, E);
  dinv_kernel<<<(N + 255) / 256, 256, 0, stream>>>(deg, dinv, N);

  // layer 1
  gemm64<128><<<(N + 63) / 64, 256, 0, stream>>>(x, W1, bufA, N);   // h1 -> bufA
  hipMemsetAsync(bufB, 0, fsz, stream);
  scatter_kernel<<<(E * 64 + 255) / 256, 256, 0, stream>>>(bufA, src, dst, dinv, bufB, E);
  epi_kernel<true><<<(n64 + 255) / 256, 256, 0, stream>>>(bufB, bufA, dinv, b1, n64);

  // layer 2
  gemm64<64><<<(N + 63) / 64, 256, 0, stream>>>(bufB, W2, bufA, N); // h2 -> bufA
  hipMemsetAsync(out, 0, fsz, stream);
  scatter_kernel<<<(E * 64 + 255) / 256, 256, 0, stream>>>(bufA, src, dst, dinv, out, E);
  epi_kernel<false><<<(n64 + 255) / 256, 256, 0, stream>>>(out, bufA, dinv, b2, n64);
}

// Round 2
// 667.640 us; speedup vs baseline: 1.2999x; 1.2999x over previous
//
#include <hip/hip_runtime.h>

// GCN 2-layer forward, CSR-based (no fp32 atomics).
// deg(dst) -> scan(rowptr,cursor,dinv) -> fill CSR(esrc) ->
// hs1=(x@W1)*dinv -> agg1(relu, self-loop, +b1) -> hs2=(.@W2)*dinv -> agg2(+b2)

__global__ __launch_bounds__(256) void deg_kernel(const int* __restrict__ dst,
                                                  int* __restrict__ deg, int nE) {
  int e = blockIdx.x * 256 + threadIdx.x;
  if (e < nE) atomicAdd(&deg[dst[e]], 1);
}

// Single-block scan over deg[N]: rowptr (exclusive), cursor (copy), dinv.
__global__ __launch_bounds__(1024) void scan_kernel(const int* __restrict__ deg,
                                                    int* __restrict__ rowptr,
                                                    int* __restrict__ cursor,
                                                    float* __restrict__ dinv, int N) {
  __shared__ int part[1024];
  const int t = threadIdx.x;
  const int chunk = (N + 1023) >> 10;
  const int lo = t * chunk, hi = min(lo + chunk, N);
  int sum = 0;
  for (int i = lo; i < hi; ++i) sum += deg[i];
  part[t] = sum;
  __syncthreads();
  for (int off = 1; off < 1024; off <<= 1) {   // Hillis-Steele inclusive scan
    int v = (t >= off) ? part[t - off] : 0;
    __syncthreads();
    part[t] += v;
    __syncthreads();
  }
  int run = (t == 0) ? 0 : part[t - 1];
  for (int i = lo; i < hi; ++i) {
    rowptr[i] = run;
    cursor[i] = run;
    int d = deg[i];
    dinv[i] = rsqrtf((float)d + 1.0f);
    run += d;
  }
  if (t == 1023) rowptr[N] = part[1023];
}

// Counting-sort edges by dst: esrc[rowptr[d]..] = src of edges into d.
__global__ __launch_bounds__(256) void fill_kernel(const int* __restrict__ src,
                                                   const int* __restrict__ dst,
                                                   int* __restrict__ cursor,
                                                   int* __restrict__ esrc, int nE) {
  int e = blockIdx.x * 256 + threadIdx.x;
  if (e < nE) {
    int p = atomicAdd(&cursor[dst[e]], 1);
    esrc[p] = src[e];
  }
}

// H[N,64] = (X[N,K] @ W[K,64]) * dinv[row].  4 rows x 4 ch per lane; W in LDS.
template <int K>
__global__ __launch_bounds__(256) void gemm64(const float* __restrict__ X,
                                              const float* __restrict__ W,
                                              const float* __restrict__ dinv,
                                              float* __restrict__ H, int N) {
  __shared__ float4 sW[K * 16];
  for (int i = threadIdx.x; i < K * 16; i += 256)
    sW[i] = reinterpret_cast<const float4*>(W)[i];
  __syncthreads();
  const int wave = threadIdx.x >> 6, lane = threadIdx.x & 63;
  const int rg = lane >> 4;
  const int cl = lane & 15;
  const int row0 = blockIdx.x * 64 + wave * 16 + rg * 4;
  if (row0 >= N) return;
  const float4* Xv = reinterpret_cast<const float4*>(X);
  const float4* xp[4];
#pragma unroll
  for (int r = 0; r < 4; ++r) {
    int row = min(row0 + r, N - 1);
    xp[r] = Xv + (size_t)row * (K / 4);
  }
  float acc[4][4] = {};
#pragma unroll 4
  for (int k4 = 0; k4 < K / 4; ++k4) {
    float4 xv[4];
#pragma unroll
    for (int r = 0; r < 4; ++r) xv[r] = xp[r][k4];
#pragma unroll
    for (int j = 0; j < 4; ++j) {
      float4 w = sW[(k4 * 4 + j) * 16 + cl];
#pragma unroll
      for (int r = 0; r < 4; ++r) {
        float xs = (&xv[r].x)[j];
        acc[r][0] += xs * w.x;
        acc[r][1] += xs * w.y;
        acc[r][2] += xs * w.z;
        acc[r][3] += xs * w.w;
      }
    }
  }
#pragma unroll
  for (int r = 0; r < 4; ++r) {
    int row = row0 + r;
    if (row < N) {
      float s = dinv[row];
      reinterpret_cast<float4*>(H)[(size_t)row * 16 + cl] =
          make_float4(acc[r][0] * s, acc[r][1] * s, acc[r][2] * s, acc[r][3] * s);
    }
  }
}

// One wave per node. hs is pre-scaled by dinv[src], so:
//   out[i] = act( dinv[i] * (sum_{k in row i} hs[esrc[k]] + hs[i]) + b )
// 4 edge-groups (g=lane>>4) x 16 lanes (cl=lane&15, float4 channels).
template <bool RELU>
__global__ __launch_bounds__(256) void agg_kernel(const float* __restrict__ hs,
                                                  const int* __restrict__ rowptr,
                                                  const int* __restrict__ esrc,
                                                  const float* __restrict__ dinv,
                                                  const float* __restrict__ b,
                                                  float* __restrict__ out, int N) {
  const int node = blockIdx.x * 4 + (threadIdx.x >> 6);
  if (node >= N) return;
  const int lane = threadIdx.x & 63;
  const int g = lane >> 4, cl = lane & 15;
  const float4* hv = reinterpret_cast<const float4*>(hs);
  const int beg = rowptr[node], end = rowptr[node + 1];
  float4 acc = make_float4(0.f, 0.f, 0.f, 0.f);
  for (int k = beg + g; k < end; k += 4) {
    int s = esrc[k];
    float4 v = hv[(size_t)s * 16 + cl];
    acc.x += v.x; acc.y += v.y; acc.z += v.z; acc.w += v.w;
  }
#pragma unroll
  for (int off = 16; off <= 32; off <<= 1) {
    acc.x += __shfl_xor(acc.x, off);
    acc.y += __shfl_xor(acc.y, off);
    acc.z += __shfl_xor(acc.z, off);
    acc.w += __shfl_xor(acc.w, off);
  }
  if (g == 0) {
    float4 self = hv[(size_t)node * 16 + cl];
    float di = dinv[node];
    float4 bb = reinterpret_cast<const float4*>(b)[cl];
    float4 r;
    r.x = (acc.x + self.x) * di + bb.x;
    r.y = (acc.y + self.y) * di + bb.y;
    r.z = (acc.z + self.z) * di + bb.z;
    r.w = (acc.w + self.w) * di + bb.w;
    if (RELU) {
      r.x = fmaxf(r.x, 0.f); r.y = fmaxf(r.y, 0.f);
      r.z = fmaxf(r.z, 0.f); r.w = fmaxf(r.w, 0.f);
    }
    reinterpret_cast<float4*>(out)[(size_t)node * 16 + cl] = r;
  }
}

extern "C" void kernel_launch(void* const* d_in, const int* in_sizes, int n_in,
                              void* d_out, int out_size, void* d_ws, size_t ws_size,
                              hipStream_t stream) {
  const float* x  = (const float*)d_in[0];
  const int*   ei = (const int*)d_in[1];
  const float* W1 = (const float*)d_in[2];
  const float* b1 = (const float*)d_in[3];
  const float* W2 = (const float*)d_in[4];
  const float* b2 = (const float*)d_in[5];
  const int N = in_sizes[0] / 128;
  const int E = in_sizes[1] / 2;
  const int* src = ei;
  const int* dst = ei + E;

  // workspace layout (all offsets 1KB-aligned):
  char* ws = (char*)d_ws;
  int*   deg    = (int*)ws;                          // N ints
  int*   rowptr = (int*)(ws + (1 << 19));            // N+1 ints @ 512KB
  int*   cursor = (int*)(ws + (1 << 20));            // N ints   @ 1MB
  float* dinv   = (float*)(ws + 3 * (1 << 19));      // N floats @ 1.5MB
  int*   esrc   = (int*)(ws + (1 << 21));            // E ints   @ 2MB (6.4MB)
  float* bufA   = (float*)(ws + 10 * (1 << 20));     // N*64 floats @ 10MB
  float* out = (float*)d_out;

  // CSR build (shared by both layers)
  hipMemsetAsync(deg, 0, N * sizeof(int), stream);
  deg_kernel<<<(E + 255) / 256, 256, 0, stream>>>(dst, deg, E);
  scan_kernel<<<1, 1024, 0, stream>>>(deg, rowptr, cursor, dinv, N);
  fill_kernel<<<(E + 255) / 256, 256, 0, stream>>>(src, dst, cursor, esrc, E);

  const int aggGrid = (N + 3) / 4;
  // layer 1: hs1 -> bufA ; agg1 -> out (temporary, becomes gemm2 input)
  gemm64<128><<<(N + 63) / 64, 256, 0, stream>>>(x, W1, dinv, bufA, N);
  agg_kernel<true><<<aggGrid, 256, 0, stream>>>(bufA, rowptr, esrc, dinv, b1, out, N);
  // layer 2: hs2 -> bufA ; agg2 -> out (final)
  gemm64<64><<<(N + 63) / 64, 256, 0, stream>>>(out, W2, dinv, bufA, N);
  agg_kernel<false><<<aggGrid, 256, 0, stream>>>(bufA, rowptr, esrc, dinv, b2, out, N);
}

// Round 3
// 398.467 us; speedup vs baseline: 2.1779x; 1.6755x over previous
//
#include <hip/hip_runtime.h>

// GCN 2-layer forward, CSR-based (no fp32 atomics), parallel scan.
// deg(dst) -> scanA/B/C(rowptr,cursor,dinv) -> fill CSR(esrc) ->
// hs1=(x@W1)*dinv -> agg1(relu,self,+b1) -> hs2=(.@W2)*dinv -> agg2(+b2)

__global__ __launch_bounds__(256) void deg_kernel(const int* __restrict__ dst,
                                                  int* __restrict__ deg, int nE) {
  int e = blockIdx.x * 256 + threadIdx.x;
  if (e < nE) atomicAdd(&deg[dst[e]], 1);
}

// Pass A: per-block sums of deg, 4096 ints per block via int4.
__global__ __launch_bounds__(1024) void scanA_kernel(const int* __restrict__ deg,
                                                     int* __restrict__ blockSums,
                                                     int nI4) {
  __shared__ int part[1024];
  int i = blockIdx.x * 1024 + threadIdx.x;
  int s = 0;
  if (i < nI4) {
    int4 v = reinterpret_cast<const int4*>(deg)[i];
    s = v.x + v.y + v.z + v.w;
  }
  part[threadIdx.x] = s;
  __syncthreads();
  for (int off = 512; off > 0; off >>= 1) {
    if (threadIdx.x < off) part[threadIdx.x] += part[threadIdx.x + off];
    __syncthreads();
  }
  if (threadIdx.x == 0) blockSums[blockIdx.x] = part[0];
}

// Pass B: exclusive scan of blockSums (tiny: <=64 blocks).
__global__ __launch_bounds__(64) void scanB_kernel(int* __restrict__ blockSums,
                                                   int nB) {
  if (threadIdx.x == 0) {
    int run = 0;
    for (int b = 0; b < nB; ++b) {
      int v = blockSums[b];
      blockSums[b] = run;
      run += v;
    }
  }
}

// Pass C: full exclusive scan; write rowptr, cursor, dinv (int4/float4 stores).
__global__ __launch_bounds__(1024) void scanC_kernel(const int* __restrict__ deg,
                                                     const int* __restrict__ blockOffs,
                                                     int* __restrict__ rowptr,
                                                     int* __restrict__ cursor,
                                                     float* __restrict__ dinv,
                                                     int nI4, int N) {
  __shared__ int part[1024];
  int i = blockIdx.x * 1024 + threadIdx.x;
  int4 v = make_int4(0, 0, 0, 0);
  if (i < nI4) v = reinterpret_cast<const int4*>(deg)[i];
  int s = v.x + v.y + v.z + v.w;
  part[threadIdx.x] = s;
  __syncthreads();
  for (int off = 1; off < 1024; off <<= 1) {   // Hillis-Steele inclusive
    int t = (threadIdx.x >= off) ? part[threadIdx.x - off] : 0;
    __syncthreads();
    part[threadIdx.x] += t;
    __syncthreads();
  }
  if (i < nI4) {
    int base = blockOffs[blockIdx.x] +
               ((threadIdx.x == 0) ? 0 : part[threadIdx.x - 1]);
    int4 r;
    r.x = base;
    r.y = r.x + v.x;
    r.z = r.y + v.y;
    r.w = r.z + v.z;
    reinterpret_cast<int4*>(rowptr)[i] = r;
    reinterpret_cast<int4*>(cursor)[i] = r;
    float4 dv;
    dv.x = rsqrtf((float)v.x + 1.0f);
    dv.y = rsqrtf((float)v.y + 1.0f);
    dv.z = rsqrtf((float)v.z + 1.0f);
    dv.w = rsqrtf((float)v.w + 1.0f);
    reinterpret_cast<float4*>(dinv)[i] = dv;
    if (i == nI4 - 1) rowptr[N] = r.w + v.w;
  }
}

// Counting-sort edges by dst.
__global__ __launch_bounds__(256) void fill_kernel(const int* __restrict__ src,
                                                   const int* __restrict__ dst,
                                                   int* __restrict__ cursor,
                                                   int* __restrict__ esrc, int nE) {
  int e = blockIdx.x * 256 + threadIdx.x;
  if (e < nE) {
    int p = atomicAdd(&cursor[dst[e]], 1);
    esrc[p] = src[e];
  }
}

// H[N,64] = (X[N,K] @ W[K,64]) * dinv[row].  4 rows x 4 ch per lane; W in LDS.
template <int K>
__global__ __launch_bounds__(256) void gemm64(const float* __restrict__ X,
                                              const float* __restrict__ W,
                                              const float* __restrict__ dinv,
                                              float* __restrict__ H, int N) {
  __shared__ float4 sW[K * 16];
  for (int i = threadIdx.x; i < K * 16; i += 256)
    sW[i] = reinterpret_cast<const float4*>(W)[i];
  __syncthreads();
  const int wave = threadIdx.x >> 6, lane = threadIdx.x & 63;
  const int rg = lane >> 4;
  const int cl = lane & 15;
  const int row0 = blockIdx.x * 64 + wave * 16 + rg * 4;
  if (row0 >= N) return;
  const float4* Xv = reinterpret_cast<const float4*>(X);
  const float4* xp[4];
#pragma unroll
  for (int r = 0; r < 4; ++r) {
    int row = min(row0 + r, N - 1);
    xp[r] = Xv + (size_t)row * (K / 4);
  }
  float acc[4][4] = {};
#pragma unroll 4
  for (int k4 = 0; k4 < K / 4; ++k4) {
    float4 xv[4];
#pragma unroll
    for (int r = 0; r < 4; ++r) xv[r] = xp[r][k4];
#pragma unroll
    for (int j = 0; j < 4; ++j) {
      float4 w = sW[(k4 * 4 + j) * 16 + cl];
#pragma unroll
      for (int r = 0; r < 4; ++r) {
        float xs = (&xv[r].x)[j];
        acc[r][0] += xs * w.x;
        acc[r][1] += xs * w.y;
        acc[r][2] += xs * w.z;
        acc[r][3] += xs * w.w;
      }
    }
  }
#pragma unroll
  for (int r = 0; r < 4; ++r) {
    int row = row0 + r;
    if (row < N) {
      float s = dinv[row];
      reinterpret_cast<float4*>(H)[(size_t)row * 16 + cl] =
          make_float4(acc[r][0] * s, acc[r][1] * s, acc[r][2] * s, acc[r][3] * s);
    }
  }
}

// One wave per node: out[i] = act(dinv[i]*(sum_edges hs[esrc] + hs[i]) + b)
template <bool RELU>
__global__ __launch_bounds__(256) void agg_kernel(const float* __restrict__ hs,
                                                  const int* __restrict__ rowptr,
                                                  const int* __restrict__ esrc,
                                                  const float* __restrict__ dinv,
                                                  const float* __restrict__ b,
                                                  float* __restrict__ out, int N) {
  const int node = blockIdx.x * 4 + (threadIdx.x >> 6);
  if (node >= N) return;
  const int lane = threadIdx.x & 63;
  const int g = lane >> 4, cl = lane & 15;
  const float4* hv = reinterpret_cast<const float4*>(hs);
  const int beg = rowptr[node], end = rowptr[node + 1];
  float4 acc = make_float4(0.f, 0.f, 0.f, 0.f);
  for (int k = beg + g; k < end; k += 4) {
    int s = esrc[k];
    float4 v = hv[(size_t)s * 16 + cl];
    acc.x += v.x; acc.y += v.y; acc.z += v.z; acc.w += v.w;
  }
#pragma unroll
  for (int off = 16; off <= 32; off <<= 1) {
    acc.x += __shfl_xor(acc.x, off);
    acc.y += __shfl_xor(acc.y, off);
    acc.z += __shfl_xor(acc.z, off);
    acc.w += __shfl_xor(acc.w, off);
  }
  if (g == 0) {
    float4 self = hv[(size_t)node * 16 + cl];
    float di = dinv[node];
    float4 bb = reinterpret_cast<const float4*>(b)[cl];
    float4 r;
    r.x = (acc.x + self.x) * di + bb.x;
    r.y = (acc.y + self.y) * di + bb.y;
    r.z = (acc.z + self.z) * di + bb.z;
    r.w = (acc.w + self.w) * di + bb.w;
    if (RELU) {
      r.x = fmaxf(r.x, 0.f); r.y = fmaxf(r.y, 0.f);
      r.z = fmaxf(r.z, 0.f); r.w = fmaxf(r.w, 0.f);
    }
    reinterpret_cast<float4*>(out)[(size_t)node * 16 + cl] = r;
  }
}

extern "C" void kernel_launch(void* const* d_in, const int* in_sizes, int n_in,
                              void* d_out, int out_size, void* d_ws, size_t ws_size,
                              hipStream_t stream) {
  const float* x  = (const float*)d_in[0];
  const int*   ei = (const int*)d_in[1];
  const float* W1 = (const float*)d_in[2];
  const float* b1 = (const float*)d_in[3];
  const float* W2 = (const float*)d_in[4];
  const float* b2 = (const float*)d_in[5];
  const int N = in_sizes[0] / 128;
  const int E = in_sizes[1] / 2;
  const int* src = ei;
  const int* dst = ei + E;

  // workspace layout (1KB-aligned offsets):
  char* ws = (char*)d_ws;
  int*   deg    = (int*)ws;                          // N ints
  int*   rowptr = (int*)(ws + (1 << 19));            // N+1 ints @ 512KB
  int*   cursor = (int*)(ws + (1 << 20));            // N ints   @ 1MB
  float* dinv   = (float*)(ws + 3 * (1 << 19));      // N floats @ 1.5MB
  int*   bsums  = (int*)(ws + 7 * (1 << 18));        // ~64 ints @ 1.75MB
  int*   esrc   = (int*)(ws + (1 << 21));            // E ints   @ 2MB
  float* bufA   = (float*)(ws + 10 * (1 << 20));     // N*64 floats @ 10MB
  float* out = (float*)d_out;

  const int nI4 = N / 4;                 // N divisible by 4 (100000)
  const int nScanB = (nI4 + 1023) / 1024;

  // CSR build (shared by both layers)
  hipMemsetAsync(deg, 0, N * sizeof(int), stream);
  deg_kernel<<<(E + 255) / 256, 256, 0, stream>>>(dst, deg, E);
  scanA_kernel<<<nScanB, 1024, 0, stream>>>(deg, bsums, nI4);
  scanB_kernel<<<1, 64, 0, stream>>>(bsums, nScanB);
  scanC_kernel<<<nScanB, 1024, 0, stream>>>(deg, bsums, rowptr, cursor, dinv, nI4, N);
  fill_kernel<<<(E + 255) / 256, 256, 0, stream>>>(src, dst, cursor, esrc, E);

  const int aggGrid = (N + 3) / 4;
  // layer 1: hs1 -> bufA ; agg1 -> out (temp, becomes gemm2 input)
  gemm64<128><<<(N + 63) / 64, 256, 0, stream>>>(x, W1, dinv, bufA, N);
  agg_kernel<true><<<aggGrid, 256, 0, stream>>>(bufA, rowptr, esrc, dinv, b1, out, N);
  // layer 2: hs2 -> bufA ; agg2 -> out (final)
  gemm64<64><<<(N + 63) / 64, 256, 0, stream>>>(out, W2, dinv, bufA, N);
  agg_kernel<false><<<aggGrid, 256, 0, stream>>>(bufA, rowptr, esrc, dinv, b2, out, N);
}